// Round 13
// baseline (123.944 us; speedup 1.0000x reference)
//
#include <hip/hip_runtime.h>

// R13 PROBE ROUND: two oversized, correct, idempotent kernels so head shows up
// in rocprof top-5 (fills are ~60us). head_full = R11 x3 passes; head_load =
// 2 pipelined load-only passes (asm keep-alive) + 1 full pass.
// reps derived from stride_p[0] (=8) at runtime -> opaque to the compiler.

typedef _Float16 half8 __attribute__((ext_vector_type(8)));
typedef __fp16  fp16x2 __attribute__((ext_vector_type(2)));
typedef float f32x4v __attribute__((ext_vector_type(4)));

constexpr int Cc = 128;
constexpr int NPAD = 96;
constexpr int WT_STRIDE = 136;
constexpr int NWAVES = 2048;         // 512 blocks * 4 waves
constexpr float LOG2E = 1.44269504088896f;

union H8 { half8 h; fp16x2 p[4]; };

__device__ __forceinline__ float sigm(float v) {
    return __builtin_amdgcn_rcpf(1.f + __builtin_amdgcn_exp2f(-LOG2E * v));
}
__device__ __forceinline__ void keep(const f32x4v& v) {
    asm volatile("" :: "v"(v));
}

// ---- shared body pieces as macros to keep both kernels identical ----
#define STAGE_WEIGHTS()                                                        \
    for (int i = tid; i < 128 * 16; i += 256) {                                \
        int k   = i >> 4;                                                      \
        int ch0 = (i & 15) << 2;                                               \
        int f   = ch0 >> 4;                                                    \
        int b0  = ch0 & 15;                                                    \
        int R0  = (b0 >> 2) * 16 + (f << 2);                                   \
        f32x4v v = *(const f32x4v*)&w_box[k * 64 + ch0];                       \
        Wt[R0 + 0][k] = (_Float16)v[0];                                        \
        Wt[R0 + 1][k] = (_Float16)v[1];                                        \
        Wt[R0 + 2][k] = (_Float16)v[2];                                        \
        Wt[R0 + 3][k] = (_Float16)v[3];                                        \
    }                                                                          \
    for (int i = tid; i < 128 * 5; i += 256) {                                 \
        int k  = i / 5;                                                        \
        int c4 = (i - k * 5) << 2;                                             \
        f32x4v v = *(const f32x4v*)&w_cls[k * 20 + c4];                        \
        Wt[64 + c4 + 0][k] = (_Float16)v[0];                                   \
        Wt[64 + c4 + 1][k] = (_Float16)v[1];                                   \
        Wt[64 + c4 + 2][k] = (_Float16)v[2];                                   \
        Wt[64 + c4 + 3][k] = (_Float16)v[3];                                   \
    }                                                                          \
    for (int i = tid; i < 12 * 128; i += 256) {                                \
        int ch = 84 + (i >> 7);                                                \
        int k  = i & 127;                                                      \
        Wt[ch][k] = (_Float16)0.f;                                             \
    }                                                                          \
    if (tid < 64) {                                                            \
        int f = tid >> 4, b = tid & 15;                                        \
        bias_s[(b >> 2) * 16 + (f << 2) + (b & 3)] = b_box[tid];               \
    } else if (tid < 96) {                                                     \
        bias_s[tid] = (tid < 84) ? b_cls[tid - 64] : 0.f;                      \
    }                                                                          \
    __syncthreads();

__global__ __launch_bounds__(256, 2)
void head_full(const float* __restrict__ x,
               const float* __restrict__ w_box,
               const float* __restrict__ b_box,
               const float* __restrict__ w_cls,
               const float* __restrict__ b_cls,
               const int*   __restrict__ stride_p,
               float* __restrict__ out)
{
    __shared__ __align__(16) _Float16 Wt[NPAD][WT_STRIDE];
    __shared__ __align__(16) float bias_s[NPAD];
    __shared__ __align__(16) float sc[4][16][24];

    const int tid  = threadIdx.x;
    const int wave = tid >> 6;
    const int lane = tid & 63;
    const int c    = lane & 15;
    const int g    = lane >> 4;

    const int reps = stride_p[0] - 5;            // 8-5 = 3, runtime-opaque
    const float sf = (float)stride_p[0];

    STAGE_WEIGHTS()

    half8 wf[4][6];
    #pragma unroll
    for (int ks = 0; ks < 4; ++ks)
        #pragma unroll
        for (int nt = 0; nt < 6; ++nt)
            wf[ks][nt] = *(const half8*)&Wt[nt * 16 + c][ks * 32 + g * 8];

    const int wid = blockIdx.x * 4 + wave;
    const bool heavy = (wave == (blockIdx.x & 3));
    const int t6 = 6 * NWAVES + blockIdx.x;

    f32x4v xvA[4][2], xvB[4][2];

    auto load_tile = [&](f32x4v (&xv)[4][2], int tile) {
        const float* xb = x + (size_t)(tile * 16 + c) * Cc + g * 8;
        #pragma unroll
        for (int ks = 0; ks < 4; ++ks) {
            const float* p = xb + ks * 32;
            xv[ks][0] = *(const f32x4v*)p;
            xv[ks][1] = *(const f32x4v*)(p + 4);
        }
        __builtin_amdgcn_sched_barrier(0);
    };

    auto compute_tile = [&](f32x4v (&xv)[4][2], int tile) {
        f32x4v acc[6];
        #pragma unroll
        for (int nt = 0; nt < 6; ++nt)
            acc[nt] = *(const f32x4v*)&bias_s[nt * 16 + g * 4];

        #pragma unroll
        for (int ks = 0; ks < 4; ++ks) {
            f32x4v lo = xv[ks][0], hi = xv[ks][1];
            H8 bu;
            bu.p[0] = __builtin_amdgcn_cvt_pkrtz(lo[0], lo[1]);
            bu.p[1] = __builtin_amdgcn_cvt_pkrtz(lo[2], lo[3]);
            bu.p[2] = __builtin_amdgcn_cvt_pkrtz(hi[0], hi[1]);
            bu.p[3] = __builtin_amdgcn_cvt_pkrtz(hi[2], hi[3]);
            #pragma unroll
            for (int nt = 0; nt < 6; ++nt)
                acc[nt] = __builtin_amdgcn_mfma_f32_16x16x32_f16(wf[ks][nt], bu.h, acc[nt], 0, 0, 0);
        }

        const int pos0 = (tile % 400) * 16;

        float s = 0.f, ws = 0.f;
        #pragma unroll
        for (int t = 0; t < 4; ++t) {
            f32x4v v = acc[t];
            float e0 = __builtin_amdgcn_exp2f(LOG2E * v[0]);
            float e1 = __builtin_amdgcn_exp2f(LOG2E * v[1]);
            float e2 = __builtin_amdgcn_exp2f(LOG2E * v[2]);
            float e3 = __builtin_amdgcn_exp2f(LOG2E * v[3]);
            s  += e0 + e1 + e2 + e3;
            ws += (float)(4 * t) * e0 + (float)(4 * t + 1) * e1
                + (float)(4 * t + 2) * e2 + (float)(4 * t + 3) * e3;
        }
        const float dfl = ws * __builtin_amdgcn_rcpf(s);

        float* rp = sc[wave][c];
        rp[g] = dfl;
        f32x4v clsA = { sigm(acc[4][0]), sigm(acc[4][1]), sigm(acc[4][2]), sigm(acc[4][3]) };
        *(f32x4v*)(rp + 4 + 4 * g) = clsA;
        if (g == 0) {
            f32x4v clsB = { sigm(acc[5][0]), sigm(acc[5][1]), sigm(acc[5][2]), sigm(acc[5][3]) };
            *(f32x4v*)(rp + 20) = clsB;
        }

        const float* s0 = &sc[wave][0][0];
        float* orow = out + (size_t)tile * (16 * 24);
        #pragma unroll
        for (int i = 0; i < 2; ++i) {
            const int j = lane + 64 * i;
            if (j < 96) {
                f32x4v v = *(const f32x4v*)(s0 + j * 4);
                const int row = j / 6;
                if (j - 6 * row == 0) {
                    const int pos = pos0 + row;
                    const int yp  = pos / 80;
                    const int xq  = pos - 80 * yp;
                    const float ax = ((float)xq + 0.5f) * sf;
                    const float ay = ((float)yp + 0.5f) * sf;
                    const float w2 = v[2] - v[0], w3 = v[3] - v[1];
                    v = (f32x4v){ ax + 0.5f * w2, ay + 0.5f * w3, w2, w3 };
                }
                *(f32x4v*)(orow + j * 4) = v;
            }
        }
    };

    const int t0 = wid,              t1 = wid + NWAVES;
    const int t2 = wid + 2 * NWAVES, t3 = wid + 3 * NWAVES;
    const int t4 = wid + 4 * NWAVES, t5 = wid + 5 * NWAVES;

    for (int r = 0; r < reps; ++r) {
        load_tile(xvA, t0);
        load_tile(xvB, t1);
        compute_tile(xvA, t0);  load_tile(xvA, t2);
        compute_tile(xvB, t1);  load_tile(xvB, t3);
        compute_tile(xvA, t2);  load_tile(xvA, t4);
        compute_tile(xvB, t3);  load_tile(xvB, t5);
        compute_tile(xvA, t4);  if (heavy) load_tile(xvA, t6);
        compute_tile(xvB, t5);
        if (heavy) compute_tile(xvA, t6);
    }
}

__global__ __launch_bounds__(256, 2)
void head_load(const float* __restrict__ x,
               const float* __restrict__ w_box,
               const float* __restrict__ b_box,
               const float* __restrict__ w_cls,
               const float* __restrict__ b_cls,
               const int*   __restrict__ stride_p,
               float* __restrict__ out)
{
    __shared__ __align__(16) _Float16 Wt[NPAD][WT_STRIDE];
    __shared__ __align__(16) float bias_s[NPAD];
    __shared__ __align__(16) float sc[4][16][24];

    const int tid  = threadIdx.x;
    const int wave = tid >> 6;
    const int lane = tid & 63;
    const int c    = lane & 15;
    const int g    = lane >> 4;

    const int reps = stride_p[0] - 5;            // 3
    const float sf = (float)stride_p[0];

    STAGE_WEIGHTS()

    half8 wf[4][6];
    #pragma unroll
    for (int ks = 0; ks < 4; ++ks)
        #pragma unroll
        for (int nt = 0; nt < 6; ++nt)
            wf[ks][nt] = *(const half8*)&Wt[nt * 16 + c][ks * 32 + g * 8];

    const int wid = blockIdx.x * 4 + wave;
    const bool heavy = (wave == (blockIdx.x & 3));
    const int t6 = 6 * NWAVES + blockIdx.x;

    f32x4v xvA[4][2], xvB[4][2];

    auto load_tile = [&](f32x4v (&xv)[4][2], int tile) {
        const float* xb = x + (size_t)(tile * 16 + c) * Cc + g * 8;
        #pragma unroll
        for (int ks = 0; ks < 4; ++ks) {
            const float* p = xb + ks * 32;
            xv[ks][0] = *(const f32x4v*)p;
            xv[ks][1] = *(const f32x4v*)(p + 4);
        }
        __builtin_amdgcn_sched_barrier(0);
    };

    auto consume_tile = [&](f32x4v (&xv)[4][2]) {   // forces vmcnt wait, no compute
        #pragma unroll
        for (int ks = 0; ks < 4; ++ks) {
            keep(xv[ks][0]);
            keep(xv[ks][1]);
        }
    };

    auto compute_tile = [&](f32x4v (&xv)[4][2], int tile) {
        f32x4v acc[6];
        #pragma unroll
        for (int nt = 0; nt < 6; ++nt)
            acc[nt] = *(const f32x4v*)&bias_s[nt * 16 + g * 4];

        #pragma unroll
        for (int ks = 0; ks < 4; ++ks) {
            f32x4v lo = xv[ks][0], hi = xv[ks][1];
            H8 bu;
            bu.p[0] = __builtin_amdgcn_cvt_pkrtz(lo[0], lo[1]);
            bu.p[1] = __builtin_amdgcn_cvt_pkrtz(lo[2], lo[3]);
            bu.p[2] = __builtin_amdgcn_cvt_pkrtz(hi[0], hi[1]);
            bu.p[3] = __builtin_amdgcn_cvt_pkrtz(hi[2], hi[3]);
            #pragma unroll
            for (int nt = 0; nt < 6; ++nt)
                acc[nt] = __builtin_amdgcn_mfma_f32_16x16x32_f16(wf[ks][nt], bu.h, acc[nt], 0, 0, 0);
        }

        const int pos0 = (tile % 400) * 16;

        float s = 0.f, ws = 0.f;
        #pragma unroll
        for (int t = 0; t < 4; ++t) {
            f32x4v v = acc[t];
            float e0 = __builtin_amdgcn_exp2f(LOG2E * v[0]);
            float e1 = __builtin_amdgcn_exp2f(LOG2E * v[1]);
            float e2 = __builtin_amdgcn_exp2f(LOG2E * v[2]);
            float e3 = __builtin_amdgcn_exp2f(LOG2E * v[3]);
            s  += e0 + e1 + e2 + e3;
            ws += (float)(4 * t) * e0 + (float)(4 * t + 1) * e1
                + (float)(4 * t + 2) * e2 + (float)(4 * t + 3) * e3;
        }
        const float dfl = ws * __builtin_amdgcn_rcpf(s);

        float* rp = sc[wave][c];
        rp[g] = dfl;
        f32x4v clsA = { sigm(acc[4][0]), sigm(acc[4][1]), sigm(acc[4][2]), sigm(acc[4][3]) };
        *(f32x4v*)(rp + 4 + 4 * g) = clsA;
        if (g == 0) {
            f32x4v clsB = { sigm(acc[5][0]), sigm(acc[5][1]), sigm(acc[5][2]), sigm(acc[5][3]) };
            *(f32x4v*)(rp + 20) = clsB;
        }

        const float* s0 = &sc[wave][0][0];
        float* orow = out + (size_t)tile * (16 * 24);
        #pragma unroll
        for (int i = 0; i < 2; ++i) {
            const int j = lane + 64 * i;
            if (j < 96) {
                f32x4v v = *(const f32x4v*)(s0 + j * 4);
                const int row = j / 6;
                if (j - 6 * row == 0) {
                    const int pos = pos0 + row;
                    const int yp  = pos / 80;
                    const int xq  = pos - 80 * yp;
                    const float ax = ((float)xq + 0.5f) * sf;
                    const float ay = ((float)yp + 0.5f) * sf;
                    const float w2 = v[2] - v[0], w3 = v[3] - v[1];
                    v = (f32x4v){ ax + 0.5f * w2, ay + 0.5f * w3, w2, w3 };
                }
                *(f32x4v*)(orow + j * 4) = v;
            }
        }
    };

    const int t0 = wid,              t1 = wid + NWAVES;
    const int t2 = wid + 2 * NWAVES, t3 = wid + 3 * NWAVES;
    const int t4 = wid + 4 * NWAVES, t5 = wid + 5 * NWAVES;

    // load-only passes (pipelined identically, vmcnt waits via keep())
    for (int r = 0; r < reps - 1; ++r) {
        load_tile(xvA, t0);
        load_tile(xvB, t1);
        consume_tile(xvA);  load_tile(xvA, t2);
        consume_tile(xvB);  load_tile(xvB, t3);
        consume_tile(xvA);  load_tile(xvA, t4);
        consume_tile(xvB);  load_tile(xvB, t5);
        consume_tile(xvA);  if (heavy) load_tile(xvA, t6);
        consume_tile(xvB);
        if (heavy) consume_tile(xvA);
    }
    // one full pass (produces the output)
    load_tile(xvA, t0);
    load_tile(xvB, t1);
    compute_tile(xvA, t0);  load_tile(xvA, t2);
    compute_tile(xvB, t1);  load_tile(xvB, t3);
    compute_tile(xvA, t2);  load_tile(xvA, t4);
    compute_tile(xvB, t3);  load_tile(xvB, t5);
    compute_tile(xvA, t4);  if (heavy) load_tile(xvA, t6);
    compute_tile(xvB, t5);
    if (heavy) compute_tile(xvA, t6);
}

extern "C" void kernel_launch(void* const* d_in, const int* in_sizes, int n_in,
                              void* d_out, int out_size, void* d_ws, size_t ws_size,
                              hipStream_t stream) {
    const float* x      = (const float*)d_in[0];
    const float* w_box  = (const float*)d_in[1];
    const float* b_box  = (const float*)d_in[2];
    const float* w_cls  = (const float*)d_in[3];
    const float* b_cls  = (const float*)d_in[4];
    const int*   stride_p = (const int*)d_in[5];
    float* out = (float*)d_out;

    dim3 grid(512), block(256);
    hipLaunchKernelGGL(head_full, grid, block, 0, stream,
                       x, w_box, b_box, w_cls, b_cls, stride_p, out);
    hipLaunchKernelGGL(head_load, grid, block, 0, stream,
                       x, w_box, b_box, w_cls, b_cls, stride_p, out);
}

// Round 14
// 35.126 us; speedup vs baseline: 3.5286x; 3.5286x over previous
//
#include <hip/hip_runtime.h>

// Head: fused GEMM (M=204800, K=128, N=84->96 padded) + DFL softmax + box decode + sigmoid.
// R14: TLP-first, spill-free. Evidence (R13 probe): kernel is latency-bound at
// 19% occupancy with scratch spill (VGPR_Count=128 < demand, WRITE 1.8x inflated).
// Changes vs R11/R12:
//   - NO wf register hoist: weight fragments read from LDS per tile (R10-style,
//     known VGPR~64-100, no spill).
//   - grid 1280 x 256, __launch_bounds__(256,4): 5 blocks/CU by LDS -> 20 waves/CU.
//   - 16-row tiles, 12800 total, 2.5/wave; even-wid waves take the extra tile
//     (uniform 50 tiles per CU).

typedef _Float16 half8 __attribute__((ext_vector_type(8)));
typedef __fp16  fp16x2 __attribute__((ext_vector_type(2)));
typedef float f32x4v __attribute__((ext_vector_type(4)));

constexpr int Cc = 128;
constexpr int NPAD = 96;
constexpr int WT_STRIDE = 136;       // 272B row; wfrag pattern -> 2-way alias (free)
constexpr int NWAVES = 5120;         // 1280 blocks * 4 waves
constexpr float LOG2E = 1.44269504088896f;

union H8 { half8 h; fp16x2 p[4]; };

__device__ __forceinline__ float sigm(float v) {
    return __builtin_amdgcn_rcpf(1.f + __builtin_amdgcn_exp2f(-LOG2E * v));
}

__global__ __launch_bounds__(256, 4)
void head_kernel(const float* __restrict__ x,
                 const float* __restrict__ w_box,
                 const float* __restrict__ b_box,
                 const float* __restrict__ w_cls,
                 const float* __restrict__ b_cls,
                 const int*   __restrict__ stride_p,
                 float* __restrict__ out)
{
    __shared__ __align__(16) _Float16 Wt[NPAD][WT_STRIDE]; // permuted box rows
    __shared__ __align__(16) float bias_s[NPAD];           // same permuted order
    __shared__ __align__(16) float sc[4][16][24];          // per-wave store-transpose scratch

    const int tid  = threadIdx.x;
    const int wave = tid >> 6;
    const int lane = tid & 63;
    const int c    = lane & 15;     // A row-in-tile sel / B spatial-row / D col
    const int g    = lane >> 4;     // quarter-group; D row = 4g + reg; g = DFL distribution

    // ---- stage Wt (box rows PERMUTED: row t*16+4f+r <- ch f*16+4t+r) ----
    for (int i = tid; i < 128 * 16; i += 256) {
        int k   = i >> 4;
        int ch0 = (i & 15) << 2;
        int f   = ch0 >> 4;
        int b0  = ch0 & 15;
        int R0  = (b0 >> 2) * 16 + (f << 2);   // t*16 + 4f
        f32x4v v = *(const f32x4v*)&w_box[k * 64 + ch0];
        Wt[R0 + 0][k] = (_Float16)v[0];
        Wt[R0 + 1][k] = (_Float16)v[1];
        Wt[R0 + 2][k] = (_Float16)v[2];
        Wt[R0 + 3][k] = (_Float16)v[3];
    }
    for (int i = tid; i < 128 * 5; i += 256) {   // cls rows 64..83 direct
        int k  = i / 5;
        int c4 = (i - k * 5) << 2;
        f32x4v v = *(const f32x4v*)&w_cls[k * 20 + c4];
        Wt[64 + c4 + 0][k] = (_Float16)v[0];
        Wt[64 + c4 + 1][k] = (_Float16)v[1];
        Wt[64 + c4 + 2][k] = (_Float16)v[2];
        Wt[64 + c4 + 3][k] = (_Float16)v[3];
    }
    for (int i = tid; i < 12 * 128; i += 256) {  // zero pad rows 84..95
        int ch = 84 + (i >> 7);
        int k  = i & 127;
        Wt[ch][k] = (_Float16)0.f;
    }
    if (tid < 64) {                              // box bias, permuted
        int f = tid >> 4, b = tid & 15;
        bias_s[(b >> 2) * 16 + (f << 2) + (b & 3)] = b_box[tid];
    } else if (tid < 96) {
        bias_s[tid] = (tid < 84) ? b_cls[tid - 64] : 0.f;
    }
    __syncthreads();

    const float sf = (float)stride_p[0];

    const int wid = blockIdx.x * 4 + wave;       // 0..5119
    const int t0 = wid, t1 = wid + NWAVES;       // [0,10240)
    const bool heavy = (wid & 1) == 0;           // even wids spread evenly across CUs
    const int t2 = 2 * NWAVES + (wid >> 1);      // [10240, 12800)

    f32x4v xvA[4][2], xvB[4][2];

    auto load_tile = [&](f32x4v (&xv)[4][2], int tile) {
        const float* xb = x + (size_t)(tile * 16 + c) * Cc + g * 8;
        #pragma unroll
        for (int ks = 0; ks < 4; ++ks) {
            const float* p = xb + ks * 32;
            xv[ks][0] = *(const f32x4v*)p;
            xv[ks][1] = *(const f32x4v*)(p + 4);
        }
        __builtin_amdgcn_sched_barrier(0);   // pin load issue here
    };

    auto compute_tile = [&](f32x4v (&xv)[4][2], int tile) {
        f32x4v acc[6];
        #pragma unroll
        for (int nt = 0; nt < 6; ++nt)
            acc[nt] = *(const f32x4v*)&bias_s[nt * 16 + g * 4];

        #pragma unroll
        for (int ks = 0; ks < 4; ++ks) {
            half8 wfrag[6];
            #pragma unroll
            for (int nt = 0; nt < 6; ++nt)
                wfrag[nt] = *(const half8*)&Wt[nt * 16 + c][ks * 32 + g * 8];
            f32x4v lo = xv[ks][0], hi = xv[ks][1];
            H8 bu;
            bu.p[0] = __builtin_amdgcn_cvt_pkrtz(lo[0], lo[1]);
            bu.p[1] = __builtin_amdgcn_cvt_pkrtz(lo[2], lo[3]);
            bu.p[2] = __builtin_amdgcn_cvt_pkrtz(hi[0], hi[1]);
            bu.p[3] = __builtin_amdgcn_cvt_pkrtz(hi[2], hi[3]);
            #pragma unroll
            for (int nt = 0; nt < 6; ++nt)
                acc[nt] = __builtin_amdgcn_mfma_f32_16x16x32_f16(wfrag[nt], bu.h, acc[nt], 0, 0, 0);
        }

        const int pos0 = (tile % 400) * 16;        // wave-uniform; never crosses y-row (80=5*16)

        // lane-local DFL softmax over all 16 bins of distribution g
        float s = 0.f, ws = 0.f;
        #pragma unroll
        for (int t = 0; t < 4; ++t) {
            f32x4v v = acc[t];
            float e0 = __builtin_amdgcn_exp2f(LOG2E * v[0]);
            float e1 = __builtin_amdgcn_exp2f(LOG2E * v[1]);
            float e2 = __builtin_amdgcn_exp2f(LOG2E * v[2]);
            float e3 = __builtin_amdgcn_exp2f(LOG2E * v[3]);
            s  += e0 + e1 + e2 + e3;
            ws += (float)(4 * t) * e0 + (float)(4 * t + 1) * e1
                + (float)(4 * t + 2) * e2 + (float)(4 * t + 3) * e3;
        }
        const float dfl = ws * __builtin_amdgcn_rcpf(s);

        float* rp = sc[wave][c];
        rp[g] = dfl;                               // raw dfl_g; decoded in writeout
        f32x4v clsA = { sigm(acc[4][0]), sigm(acc[4][1]), sigm(acc[4][2]), sigm(acc[4][3]) };
        *(f32x4v*)(rp + 4 + 4 * g) = clsA;
        if (g == 0) {
            f32x4v clsB = { sigm(acc[5][0]), sigm(acc[5][1]), sigm(acc[5][2]), sigm(acc[5][3]) };
            *(f32x4v*)(rp + 20) = clsB;
        }

        // dense write-out: 16 rows x 24 floats = 96 float4s; field==0 gets box decode
        const float* s0 = &sc[wave][0][0];
        float* orow = out + (size_t)tile * (16 * 24);
        #pragma unroll
        for (int i = 0; i < 2; ++i) {
            const int j = lane + 64 * i;
            if (j < 96) {
                f32x4v v = *(const f32x4v*)(s0 + j * 4);
                const int row = j / 6;
                if (j - 6 * row == 0) {
                    const int pos = pos0 + row;
                    const int yp  = pos / 80;
                    const int xq  = pos - 80 * yp;
                    const float ax = ((float)xq + 0.5f) * sf;
                    const float ay = ((float)yp + 0.5f) * sf;
                    const float w2 = v[2] - v[0], w3 = v[3] - v[1];
                    v = (f32x4v){ ax + 0.5f * w2, ay + 0.5f * w3, w2, w3 };
                }
                *(f32x4v*)(orow + j * 4) = v;
            }
        }
    };

    // ---- 2-deep pipeline over 2-3 tiles; TLP (20 waves/CU) hides the rest ----
    load_tile(xvA, t0);
    load_tile(xvB, t1);
    compute_tile(xvA, t0);
    if (heavy) load_tile(xvA, t2);
    compute_tile(xvB, t1);
    if (heavy) compute_tile(xvA, t2);
}

extern "C" void kernel_launch(void* const* d_in, const int* in_sizes, int n_in,
                              void* d_out, int out_size, void* d_ws, size_t ws_size,
                              hipStream_t stream) {
    const float* x      = (const float*)d_in[0];
    const float* w_box  = (const float*)d_in[1];
    const float* b_box  = (const float*)d_in[2];
    const float* w_cls  = (const float*)d_in[3];
    const float* b_cls  = (const float*)d_in[4];
    const int*   stride_p = (const int*)d_in[5];
    float* out = (float*)d_out;

    dim3 grid(1280), block(256);
    hipLaunchKernelGGL(head_kernel, grid, block, 0, stream,
                       x, w_box, b_box, w_cls, b_cls, stride_p, out);
}

// Round 15
// 30.361 us; speedup vs baseline: 4.0824x; 1.1569x over previous
//
#include <hip/hip_runtime.h>

// Head: fused GEMM (M=204800, K=128, N=84->96) + DFL softmax + box decode + sigmoid.
// R15: 8-wave blocks (512 thr), grid 512 -> exactly 2 blocks/CU, 16 waves/CU
// (2x R11 TLP) while keeping staging amortization at 25 tiles/block.
// __launch_bounds__(512,4): VGPR cap 128, demand ~124 -> no spill (R13 lesson).
// Direct wave-covered epilogue stores (R2-proven 19.2MB) + tiny scdfl LDS
// round-trip for box assembly; shfl-free; VALU diet (exp2/rcp/cvt_pkrtz).

typedef _Float16 half8 __attribute__((ext_vector_type(8)));
typedef __fp16  fp16x2 __attribute__((ext_vector_type(2)));
typedef float f32x4v __attribute__((ext_vector_type(4)));

constexpr int Cc = 128;
constexpr int NPAD = 96;
constexpr int WT_STRIDE = 136;       // 272B row -> 2-way bank alias on wfrag reads (free)
constexpr int NWAVES = 4096;         // 512 blocks * 8 waves
constexpr float LOG2E = 1.44269504088896f;

union H8 { half8 h; fp16x2 p[4]; };

__device__ __forceinline__ float sigm(float v) {
    return __builtin_amdgcn_rcpf(1.f + __builtin_amdgcn_exp2f(-LOG2E * v));
}

__global__ __launch_bounds__(512, 4)
void head_kernel(const float* __restrict__ x,
                 const float* __restrict__ w_box,
                 const float* __restrict__ b_box,
                 const float* __restrict__ w_cls,
                 const float* __restrict__ b_cls,
                 const int*   __restrict__ stride_p,
                 float* __restrict__ out)
{
    __shared__ __align__(16) _Float16 Wt[NPAD][WT_STRIDE]; // permuted box rows
    __shared__ __align__(16) float bias_s[NPAD];           // same permuted order
    __shared__ __align__(16) float scdfl[8][16][4];        // per-wave dfl exchange (2KB)

    const int tid  = threadIdx.x;
    const int wave = tid >> 6;      // 0..7
    const int lane = tid & 63;
    const int c    = lane & 15;     // B spatial-row / D col
    const int g    = lane >> 4;     // D row = 4g+reg; g = DFL distribution id

    // ---- stage Wt (box rows PERMUTED: row t*16+4f+r <- ch f*16+4t+r) ----
    for (int i = tid; i < 128 * 16; i += 512) {
        int k   = i >> 4;
        int ch0 = (i & 15) << 2;
        int f   = ch0 >> 4;
        int b0  = ch0 & 15;
        int R0  = (b0 >> 2) * 16 + (f << 2);   // t*16 + 4f
        f32x4v v = *(const f32x4v*)&w_box[k * 64 + ch0];
        Wt[R0 + 0][k] = (_Float16)v[0];
        Wt[R0 + 1][k] = (_Float16)v[1];
        Wt[R0 + 2][k] = (_Float16)v[2];
        Wt[R0 + 3][k] = (_Float16)v[3];
    }
    for (int i = tid; i < 128 * 5; i += 512) {   // cls rows 64..83 direct
        int k  = i / 5;
        int c4 = (i - k * 5) << 2;
        f32x4v v = *(const f32x4v*)&w_cls[k * 20 + c4];
        Wt[64 + c4 + 0][k] = (_Float16)v[0];
        Wt[64 + c4 + 1][k] = (_Float16)v[1];
        Wt[64 + c4 + 2][k] = (_Float16)v[2];
        Wt[64 + c4 + 3][k] = (_Float16)v[3];
    }
    for (int i = tid; i < 12 * 128; i += 512) {  // zero pad rows 84..95
        int ch = 84 + (i >> 7);
        int k  = i & 127;
        Wt[ch][k] = (_Float16)0.f;
    }
    if (tid < 64) {                              // box bias, permuted
        int f = tid >> 4, b = tid & 15;
        bias_s[(b >> 2) * 16 + (f << 2) + (b & 3)] = b_box[tid];
    } else if (tid < 96) {
        bias_s[tid] = (tid < 84) ? b_cls[tid - 64] : 0.f;
    }
    __syncthreads();

    const float sf = (float)stride_p[0];

    const int wid = blockIdx.x * 8 + wave;       // 0..4095
    const int t0 = wid, t1 = wid + NWAVES, t2 = wid + 2 * NWAVES;  // [0,12288)
    const bool heavy = (wid & 7) == 0;           // one per block -> uniform per CU
    const int t3 = 3 * NWAVES + (wid >> 3);      // [12288, 12800)

    f32x4v xvA[4][2], xvB[4][2];

    auto load_tile = [&](f32x4v (&xv)[4][2], int tile) {
        const float* xb = x + (size_t)(tile * 16 + c) * Cc + g * 8;
        #pragma unroll
        for (int ks = 0; ks < 4; ++ks) {
            const float* p = xb + ks * 32;
            xv[ks][0] = *(const f32x4v*)p;
            xv[ks][1] = *(const f32x4v*)(p + 4);
        }
        __builtin_amdgcn_sched_barrier(0);   // pin load issue here
    };

    auto compute_tile = [&](f32x4v (&xv)[4][2], int tile) {
        f32x4v acc[6];
        #pragma unroll
        for (int nt = 0; nt < 6; ++nt)
            acc[nt] = *(const f32x4v*)&bias_s[nt * 16 + g * 4];

        #pragma unroll
        for (int ks = 0; ks < 4; ++ks) {
            half8 wfrag[6];
            #pragma unroll
            for (int nt = 0; nt < 6; ++nt)
                wfrag[nt] = *(const half8*)&Wt[nt * 16 + c][ks * 32 + g * 8];
            f32x4v lo = xv[ks][0], hi = xv[ks][1];
            H8 bu;
            bu.p[0] = __builtin_amdgcn_cvt_pkrtz(lo[0], lo[1]);
            bu.p[1] = __builtin_amdgcn_cvt_pkrtz(lo[2], lo[3]);
            bu.p[2] = __builtin_amdgcn_cvt_pkrtz(hi[0], hi[1]);
            bu.p[3] = __builtin_amdgcn_cvt_pkrtz(hi[2], hi[3]);
            #pragma unroll
            for (int nt = 0; nt < 6; ++nt)
                acc[nt] = __builtin_amdgcn_mfma_f32_16x16x32_f16(wfrag[nt], bu.h, acc[nt], 0, 0, 0);
        }

        // lane-local DFL softmax over all 16 bins of distribution g
        float s = 0.f, ws = 0.f;
        #pragma unroll
        for (int t = 0; t < 4; ++t) {
            f32x4v v = acc[t];
            float e0 = __builtin_amdgcn_exp2f(LOG2E * v[0]);
            float e1 = __builtin_amdgcn_exp2f(LOG2E * v[1]);
            float e2 = __builtin_amdgcn_exp2f(LOG2E * v[2]);
            float e3 = __builtin_amdgcn_exp2f(LOG2E * v[3]);
            s  += e0 + e1 + e2 + e3;
            ws += (float)(4 * t) * e0 + (float)(4 * t + 1) * e1
                + (float)(4 * t + 2) * e2 + (float)(4 * t + 3) * e3;
        }
        const float dfl = ws * __builtin_amdgcn_rcpf(s);

        // exchange dfl across g within the wave (tiny LDS round-trip, no shfl)
        scdfl[wave][c][g] = dfl;
        f32x4v db = *(const f32x4v*)&scdfl[wave][c][0];   // broadcast to 4 g-lanes

        const int pos0 = (tile % 400) * 16;    // rows stay in one y-line (80 = 5*16)
        const int yp   = pos0 / 80;
        const int xq   = (pos0 - 80 * yp) + c;
        const float ax = ((float)xq + 0.5f) * sf;
        const float ay = ((float)yp + 0.5f) * sf;
        const float w2 = db[2] - db[0], w3 = db[3] - db[1];

        float* op = out + (size_t)(tile * 16 + c) * 24;

        f32x4v clsA = { sigm(acc[4][0]), sigm(acc[4][1]), sigm(acc[4][2]), sigm(acc[4][3]) };
        *(f32x4v*)(op + 4 + 4 * g) = clsA;
        if (g == 0) {
            f32x4v box = { ax + 0.5f * w2, ay + 0.5f * w3, w2, w3 };
            *(f32x4v*)op = box;
            f32x4v clsB = { sigm(acc[5][0]), sigm(acc[5][1]), sigm(acc[5][2]), sigm(acc[5][3]) };
            *(f32x4v*)(op + 20) = clsB;
        }
    };

    // ---- 2-deep pipeline; TLP (16 waves/CU) hides the rest ----
    load_tile(xvA, t0);
    load_tile(xvB, t1);
    compute_tile(xvA, t0);  load_tile(xvA, t2);
    compute_tile(xvB, t1);  if (heavy) load_tile(xvB, t3);
    compute_tile(xvA, t2);
    if (heavy) compute_tile(xvB, t3);
}

extern "C" void kernel_launch(void* const* d_in, const int* in_sizes, int n_in,
                              void* d_out, int out_size, void* d_ws, size_t ws_size,
                              hipStream_t stream) {
    const float* x      = (const float*)d_in[0];
    const float* w_box  = (const float*)d_in[1];
    const float* b_box  = (const float*)d_in[2];
    const float* w_cls  = (const float*)d_in[3];
    const float* b_cls  = (const float*)d_in[4];
    const int*   stride_p = (const int*)d_in[5];
    float* out = (float*)d_out;

    dim3 grid(512), block(512);
    hipLaunchKernelGGL(head_kernel, grid, block, 0, stream,
                       x, w_box, b_box, w_cls, b_cls, stride_p, out);
}

// Round 16
// 28.362 us; speedup vs baseline: 4.3701x; 1.0705x over previous
//
#include <hip/hip_runtime.h>

// Head: fused GEMM (M=204800, K=128, N=84->96) + DFL softmax + box decode + sigmoid.
// R16 = R11 geometry (256thr blocks, grid 512, 2 blocks/CU, 25 tiles/block)
//     + NO wf hoist (VGPR demand ~175 < 256 cap -> no scratch spill, R13 lesson)
//     + 3-deep register pipeline (the R12 test, valid now that it fits)
//     + R15's lean epilogue (scdfl LDS exchange + direct wave-covered stores).

typedef _Float16 half8 __attribute__((ext_vector_type(8)));
typedef __fp16  fp16x2 __attribute__((ext_vector_type(2)));
typedef float f32x4v __attribute__((ext_vector_type(4)));

constexpr int Cc = 128;
constexpr int NPAD = 96;
constexpr int WT_STRIDE = 136;       // 272B row -> 2-way bank alias on wfrag reads (free)
constexpr int NWAVES = 2048;         // 512 blocks * 4 waves
constexpr float LOG2E = 1.44269504088896f;

union H8 { half8 h; fp16x2 p[4]; };

__device__ __forceinline__ float sigm(float v) {
    return __builtin_amdgcn_rcpf(1.f + __builtin_amdgcn_exp2f(-LOG2E * v));
}

__global__ __launch_bounds__(256, 2)
void head_kernel(const float* __restrict__ x,
                 const float* __restrict__ w_box,
                 const float* __restrict__ b_box,
                 const float* __restrict__ w_cls,
                 const float* __restrict__ b_cls,
                 const int*   __restrict__ stride_p,
                 float* __restrict__ out)
{
    __shared__ __align__(16) _Float16 Wt[NPAD][WT_STRIDE]; // permuted box rows
    __shared__ __align__(16) float bias_s[NPAD];           // same permuted order
    __shared__ __align__(16) float scdfl[4][16][4];        // per-wave dfl exchange (1KB)

    const int tid  = threadIdx.x;
    const int wave = tid >> 6;      // 0..3
    const int lane = tid & 63;
    const int c    = lane & 15;     // B spatial-row / D col
    const int g    = lane >> 4;     // D row = 4g+reg; g = DFL distribution id

    // ---- stage Wt (box rows PERMUTED: row t*16+4f+r <- ch f*16+4t+r) ----
    for (int i = tid; i < 128 * 16; i += 256) {
        int k   = i >> 4;
        int ch0 = (i & 15) << 2;
        int f   = ch0 >> 4;
        int b0  = ch0 & 15;
        int R0  = (b0 >> 2) * 16 + (f << 2);   // t*16 + 4f
        f32x4v v = *(const f32x4v*)&w_box[k * 64 + ch0];
        Wt[R0 + 0][k] = (_Float16)v[0];
        Wt[R0 + 1][k] = (_Float16)v[1];
        Wt[R0 + 2][k] = (_Float16)v[2];
        Wt[R0 + 3][k] = (_Float16)v[3];
    }
    for (int i = tid; i < 128 * 5; i += 256) {   // cls rows 64..83 direct
        int k  = i / 5;
        int c4 = (i - k * 5) << 2;
        f32x4v v = *(const f32x4v*)&w_cls[k * 20 + c4];
        Wt[64 + c4 + 0][k] = (_Float16)v[0];
        Wt[64 + c4 + 1][k] = (_Float16)v[1];
        Wt[64 + c4 + 2][k] = (_Float16)v[2];
        Wt[64 + c4 + 3][k] = (_Float16)v[3];
    }
    for (int i = tid; i < 12 * 128; i += 256) {  // zero pad rows 84..95
        int ch = 84 + (i >> 7);
        int k  = i & 127;
        Wt[ch][k] = (_Float16)0.f;
    }
    if (tid < 64) {                              // box bias, permuted
        int f = tid >> 4, b = tid & 15;
        bias_s[(b >> 2) * 16 + (f << 2) + (b & 3)] = b_box[tid];
    } else if (tid < 96) {
        bias_s[tid] = (tid < 84) ? b_cls[tid - 64] : 0.f;
    }
    __syncthreads();

    const float sf = (float)stride_p[0];

    const int wid = blockIdx.x * 4 + wave;       // 0..2047
    const int t0 = wid,              t1 = wid + NWAVES;
    const int t2 = wid + 2 * NWAVES, t3 = wid + 3 * NWAVES;
    const int t4 = wid + 4 * NWAVES, t5 = wid + 5 * NWAVES;   // [0, 12288)
    const bool heavy = (wave == (blockIdx.x & 3));            // 1 per block
    const int t6 = 6 * NWAVES + blockIdx.x;                   // [12288, 12800)

    f32x4v xvA[4][2], xvB[4][2], xvC[4][2];

    auto load_tile = [&](f32x4v (&xv)[4][2], int tile) {
        const float* xb = x + (size_t)(tile * 16 + c) * Cc + g * 8;
        #pragma unroll
        for (int ks = 0; ks < 4; ++ks) {
            const float* p = xb + ks * 32;
            xv[ks][0] = *(const f32x4v*)p;
            xv[ks][1] = *(const f32x4v*)(p + 4);
        }
        __builtin_amdgcn_sched_barrier(0);   // pin load issue here
    };

    auto compute_tile = [&](f32x4v (&xv)[4][2], int tile) {
        f32x4v acc[6];
        #pragma unroll
        for (int nt = 0; nt < 6; ++nt)
            acc[nt] = *(const f32x4v*)&bias_s[nt * 16 + g * 4];

        #pragma unroll
        for (int ks = 0; ks < 4; ++ks) {
            half8 wfrag[6];
            #pragma unroll
            for (int nt = 0; nt < 6; ++nt)
                wfrag[nt] = *(const half8*)&Wt[nt * 16 + c][ks * 32 + g * 8];
            f32x4v lo = xv[ks][0], hi = xv[ks][1];
            H8 bu;
            bu.p[0] = __builtin_amdgcn_cvt_pkrtz(lo[0], lo[1]);
            bu.p[1] = __builtin_amdgcn_cvt_pkrtz(lo[2], lo[3]);
            bu.p[2] = __builtin_amdgcn_cvt_pkrtz(hi[0], hi[1]);
            bu.p[3] = __builtin_amdgcn_cvt_pkrtz(hi[2], hi[3]);
            #pragma unroll
            for (int nt = 0; nt < 6; ++nt)
                acc[nt] = __builtin_amdgcn_mfma_f32_16x16x32_f16(wfrag[nt], bu.h, acc[nt], 0, 0, 0);
        }

        // lane-local DFL softmax over all 16 bins of distribution g
        float s = 0.f, ws = 0.f;
        #pragma unroll
        for (int t = 0; t < 4; ++t) {
            f32x4v v = acc[t];
            float e0 = __builtin_amdgcn_exp2f(LOG2E * v[0]);
            float e1 = __builtin_amdgcn_exp2f(LOG2E * v[1]);
            float e2 = __builtin_amdgcn_exp2f(LOG2E * v[2]);
            float e3 = __builtin_amdgcn_exp2f(LOG2E * v[3]);
            s  += e0 + e1 + e2 + e3;
            ws += (float)(4 * t) * e0 + (float)(4 * t + 1) * e1
                + (float)(4 * t + 2) * e2 + (float)(4 * t + 3) * e3;
        }
        const float dfl = ws * __builtin_amdgcn_rcpf(s);

        // exchange dfl across g within the wave (tiny LDS round-trip, no shfl)
        scdfl[wave][c][g] = dfl;
        f32x4v db = *(const f32x4v*)&scdfl[wave][c][0];

        const int pos0 = (tile % 400) * 16;    // rows stay in one y-line (80 = 5*16)
        const int yp   = pos0 / 80;
        const int xq   = (pos0 - 80 * yp) + c;
        const float ax = ((float)xq + 0.5f) * sf;
        const float ay = ((float)yp + 0.5f) * sf;
        const float w2 = db[2] - db[0], w3 = db[3] - db[1];

        float* op = out + (size_t)(tile * 16 + c) * 24;

        f32x4v clsA = { sigm(acc[4][0]), sigm(acc[4][1]), sigm(acc[4][2]), sigm(acc[4][3]) };
        *(f32x4v*)(op + 4 + 4 * g) = clsA;
        if (g == 0) {
            f32x4v box = { ax + 0.5f * w2, ay + 0.5f * w3, w2, w3 };
            *(f32x4v*)op = box;
            f32x4v clsB = { sigm(acc[5][0]), sigm(acc[5][1]), sigm(acc[5][2]), sigm(acc[5][3]) };
            *(f32x4v*)(op + 20) = clsB;
        }
    };

    // ---- 3-deep pipeline: 2 tiles of loads (16 dwordx4) in flight throughout ----
    load_tile(xvA, t0);
    load_tile(xvB, t1);
    load_tile(xvC, t2);
    compute_tile(xvA, t0);  load_tile(xvA, t3);
    compute_tile(xvB, t1);  load_tile(xvB, t4);
    compute_tile(xvC, t2);  load_tile(xvC, t5);
    compute_tile(xvA, t3);  if (heavy) load_tile(xvA, t6);
    compute_tile(xvB, t4);
    compute_tile(xvC, t5);
    if (heavy) compute_tile(xvA, t6);
}

extern "C" void kernel_launch(void* const* d_in, const int* in_sizes, int n_in,
                              void* d_out, int out_size, void* d_ws, size_t ws_size,
                              hipStream_t stream) {
    const float* x      = (const float*)d_in[0];
    const float* w_box  = (const float*)d_in[1];
    const float* b_box  = (const float*)d_in[2];
    const float* w_cls  = (const float*)d_in[3];
    const float* b_cls  = (const float*)d_in[4];
    const int*   stride_p = (const int*)d_in[5];
    float* out = (float*)d_out;

    dim3 grid(512), block(256);
    hipLaunchKernelGGL(head_kernel, grid, block, 0, stream,
                       x, w_box, b_box, w_cls, b_cls, stride_p, out);
}

// Round 17
// 26.845 us; speedup vs baseline: 4.6169x; 1.0565x over previous
//
#include <hip/hip_runtime.h>

// Head: fused GEMM (M=204800, K=128, N=84->96) + DFL softmax + box decode + sigmoid.
// R17 = R16 + wf register hoist WITHOUT spill + prologue LDS-write diet:
//   - __launch_bounds__(256,1): lets the compiler allocate >128 VGPRs (R13 showed
//     a 128-reg heuristic cap at (256,2) which forced scratch spill on the hoist).
//   - wf[4][6] half8 read once per wave; main loop has ZERO LDS reads.
//   - 2-deep pipeline (R16 proved 3-deep adds nothing; keeps demand ~215 < 256).
//   - staging via packed ds_write_b64 (4 k per item, conflict-free mapping) and
//     b128 zero-pad: ~4x fewer LDS write instrs (R13: 1.8M conflict-cycles).
//   - t0/t1 x-loads issued before staging to overlap the prologue.

typedef _Float16 half8 __attribute__((ext_vector_type(8)));
typedef _Float16 half4 __attribute__((ext_vector_type(4)));
typedef __fp16  fp16x2 __attribute__((ext_vector_type(2)));
typedef float f32x4v __attribute__((ext_vector_type(4)));

constexpr int Cc = 128;
constexpr int NPAD = 96;
constexpr int WT_STRIDE = 136;       // f16; 272B row, 8B-aligned for b64 column writes
constexpr int NWAVES = 2048;         // 512 blocks * 4 waves
constexpr float LOG2E = 1.44269504088896f;

union H8 { half8 h; fp16x2 p[4]; };

__device__ __forceinline__ float sigm(float v) {
    return __builtin_amdgcn_rcpf(1.f + __builtin_amdgcn_exp2f(-LOG2E * v));
}

__global__ __launch_bounds__(256, 1)
void head_kernel(const float* __restrict__ x,
                 const float* __restrict__ w_box,
                 const float* __restrict__ b_box,
                 const float* __restrict__ w_cls,
                 const float* __restrict__ b_cls,
                 const int*   __restrict__ stride_p,
                 float* __restrict__ out)
{
    __shared__ __align__(16) _Float16 Wt[NPAD][WT_STRIDE]; // permuted box rows
    __shared__ __align__(16) float bias_s[NPAD];           // same permuted order
    __shared__ __align__(16) float scdfl[4][16][4];        // per-wave dfl exchange (1KB)

    const int tid  = threadIdx.x;
    const int wave = tid >> 6;      // 0..3
    const int lane = tid & 63;
    const int c    = lane & 15;     // B spatial-row / D col
    const int g    = lane >> 4;     // D row = 4g+reg; g = DFL distribution id

    const int wid = blockIdx.x * 4 + wave;       // 0..2047
    const int t0 = wid,              t1 = wid + NWAVES;
    const int t2 = wid + 2 * NWAVES, t3 = wid + 3 * NWAVES;
    const int t4 = wid + 4 * NWAVES, t5 = wid + 5 * NWAVES;   // [0, 12288)
    const bool heavy = (wave == (blockIdx.x & 3));            // 1 per block
    const int t6 = 6 * NWAVES + blockIdx.x;                   // [12288, 12800)

    f32x4v xvA[4][2], xvB[4][2];

    auto load_tile = [&](f32x4v (&xv)[4][2], int tile) {
        const float* xb = x + (size_t)(tile * 16 + c) * Cc + g * 8;
        #pragma unroll
        for (int ks = 0; ks < 4; ++ks) {
            const float* p = xb + ks * 32;
            xv[ks][0] = *(const f32x4v*)p;
            xv[ks][1] = *(const f32x4v*)(p + 4);
        }
        __builtin_amdgcn_sched_barrier(0);   // pin load issue here
    };

    // ---- issue first 2 tiles' loads BEFORE staging (overlap prologue) ----
    load_tile(xvA, t0);
    load_tile(xvB, t1);

    // ---- stage Wt (box rows PERMUTED: row t*16+4f+r <- ch f*16+4t+r) ----
    // box: 512 items = 16 ch0-groups x 32 k-groups; 4 k's packed per b64 write.
    for (int i = tid; i < 512; i += 256) {
        int ch0 = (i >> 5) << 2;               // 0,4,..,60
        int k0  = (i & 31) << 2;               // 0,4,..,124
        int f   = ch0 >> 4;
        int b0  = ch0 & 15;
        int R0  = (b0 >> 2) * 16 + (f << 2);   // t*16 + 4f
        f32x4v v0 = *(const f32x4v*)&w_box[(k0 + 0) * 64 + ch0];
        f32x4v v1 = *(const f32x4v*)&w_box[(k0 + 1) * 64 + ch0];
        f32x4v v2 = *(const f32x4v*)&w_box[(k0 + 2) * 64 + ch0];
        f32x4v v3 = *(const f32x4v*)&w_box[(k0 + 3) * 64 + ch0];
        #pragma unroll
        for (int r = 0; r < 4; ++r) {
            half4 h = { (_Float16)v0[r], (_Float16)v1[r], (_Float16)v2[r], (_Float16)v3[r] };
            *(half4*)&Wt[R0 + r][k0] = h;
        }
    }
    // cls: 160 items = 5 ch0-groups x 32 k-groups
    for (int i = tid; i < 160; i += 256) {
        int ch0 = (i / 32) << 2;               // 0,4,8,12,16
        int k0  = (i & 31) << 2;
        f32x4v v0 = *(const f32x4v*)&w_cls[(k0 + 0) * 20 + ch0];
        f32x4v v1 = *(const f32x4v*)&w_cls[(k0 + 1) * 20 + ch0];
        f32x4v v2 = *(const f32x4v*)&w_cls[(k0 + 2) * 20 + ch0];
        f32x4v v3 = *(const f32x4v*)&w_cls[(k0 + 3) * 20 + ch0];
        #pragma unroll
        for (int r = 0; r < 4; ++r) {
            half4 h = { (_Float16)v0[r], (_Float16)v1[r], (_Float16)v2[r], (_Float16)v3[r] };
            *(half4*)&Wt[64 + ch0 + r][k0] = h;
        }
    }
    // zero pad rows 84..95: 12 rows x 128 f16 = 12 x 32 b64-chunks
    for (int i = tid; i < 12 * 16; i += 256) {   // b128 chunks: 128 f16 = 16 x8
        int ch = 84 + (i >> 4);
        int k0 = (i & 15) << 3;
        *(f32x4v*)&Wt[ch][k0] = (f32x4v){0.f, 0.f, 0.f, 0.f};
    }
    if (tid < 64) {                              // box bias, permuted
        int f = tid >> 4, b = tid & 15;
        bias_s[(b >> 2) * 16 + (f << 2) + (b & 3)] = b_box[tid];
    } else if (tid < 96) {
        bias_s[tid] = (tid < 84) ? b_cls[tid - 64] : 0.f;
    }
    __syncthreads();

    // ---- hoist weight fragments into registers ONCE (24 ds_read_b128) ----
    half8 wf[4][6];
    #pragma unroll
    for (int ks = 0; ks < 4; ++ks)
        #pragma unroll
        for (int nt = 0; nt < 6; ++nt)
            wf[ks][nt] = *(const half8*)&Wt[nt * 16 + c][ks * 32 + g * 8];

    const float sf = (float)stride_p[0];

    auto compute_tile = [&](f32x4v (&xv)[4][2], int tile) {
        f32x4v acc[6];
        #pragma unroll
        for (int nt = 0; nt < 6; ++nt)
            acc[nt] = *(const f32x4v*)&bias_s[nt * 16 + g * 4];

        #pragma unroll
        for (int ks = 0; ks < 4; ++ks) {
            f32x4v lo = xv[ks][0], hi = xv[ks][1];
            H8 bu;
            bu.p[0] = __builtin_amdgcn_cvt_pkrtz(lo[0], lo[1]);
            bu.p[1] = __builtin_amdgcn_cvt_pkrtz(lo[2], lo[3]);
            bu.p[2] = __builtin_amdgcn_cvt_pkrtz(hi[0], hi[1]);
            bu.p[3] = __builtin_amdgcn_cvt_pkrtz(hi[2], hi[3]);
            #pragma unroll
            for (int nt = 0; nt < 6; ++nt)
                acc[nt] = __builtin_amdgcn_mfma_f32_16x16x32_f16(wf[ks][nt], bu.h, acc[nt], 0, 0, 0);
        }

        // lane-local DFL softmax over all 16 bins of distribution g
        float s = 0.f, ws = 0.f;
        #pragma unroll
        for (int t = 0; t < 4; ++t) {
            f32x4v v = acc[t];
            float e0 = __builtin_amdgcn_exp2f(LOG2E * v[0]);
            float e1 = __builtin_amdgcn_exp2f(LOG2E * v[1]);
            float e2 = __builtin_amdgcn_exp2f(LOG2E * v[2]);
            float e3 = __builtin_amdgcn_exp2f(LOG2E * v[3]);
            s  += e0 + e1 + e2 + e3;
            ws += (float)(4 * t) * e0 + (float)(4 * t + 1) * e1
                + (float)(4 * t + 2) * e2 + (float)(4 * t + 3) * e3;
        }
        const float dfl = ws * __builtin_amdgcn_rcpf(s);

        // exchange dfl across g within the wave (tiny LDS round-trip, no shfl)
        scdfl[wave][c][g] = dfl;
        f32x4v db = *(const f32x4v*)&scdfl[wave][c][0];

        const int pos0 = (tile % 400) * 16;    // rows stay in one y-line (80 = 5*16)
        const int yp   = pos0 / 80;
        const int xq   = (pos0 - 80 * yp) + c;
        const float ax = ((float)xq + 0.5f) * sf;
        const float ay = ((float)yp + 0.5f) * sf;
        const float w2 = db[2] - db[0], w3 = db[3] - db[1];

        float* op = out + (size_t)(tile * 16 + c) * 24;

        f32x4v clsA = { sigm(acc[4][0]), sigm(acc[4][1]), sigm(acc[4][2]), sigm(acc[4][3]) };
        *(f32x4v*)(op + 4 + 4 * g) = clsA;
        if (g == 0) {
            f32x4v box = { ax + 0.5f * w2, ay + 0.5f * w3, w2, w3 };
            *(f32x4v*)op = box;
            f32x4v clsB = { sigm(acc[5][0]), sigm(acc[5][1]), sigm(acc[5][2]), sigm(acc[5][3]) };
            *(f32x4v*)(op + 20) = clsB;
        }
    };

    // ---- 2-deep pipeline over 6-7 tiles ----
    compute_tile(xvA, t0);  load_tile(xvA, t2);
    compute_tile(xvB, t1);  load_tile(xvB, t3);
    compute_tile(xvA, t2);  load_tile(xvA, t4);
    compute_tile(xvB, t3);  load_tile(xvB, t5);
    compute_tile(xvA, t4);  if (heavy) load_tile(xvA, t6);
    compute_tile(xvB, t5);
    if (heavy) compute_tile(xvA, t6);
}

extern "C" void kernel_launch(void* const* d_in, const int* in_sizes, int n_in,
                              void* d_out, int out_size, void* d_ws, size_t ws_size,
                              hipStream_t stream) {
    const float* x      = (const float*)d_in[0];
    const float* w_box  = (const float*)d_in[1];
    const float* b_box  = (const float*)d_in[2];
    const float* w_cls  = (const float*)d_in[3];
    const float* b_cls  = (const float*)d_in[4];
    const int*   stride_p = (const int*)d_in[5];
    float* out = (float*)d_out;

    dim3 grid(512), block(256);
    hipLaunchKernelGGL(head_kernel, grid, block, 0, stream,
                       x, w_box, b_box, w_cls, b_cls, stride_p, out);
}